// Round 1
// 210.616 us; speedup vs baseline: 1.5016x; 1.5016x over previous
//
#include <hip/hip_runtime.h>
#include <hip/hip_bf16.h>

#define D 256

typedef __attribute__((ext_vector_type(8))) short bf16x8;
typedef __attribute__((ext_vector_type(4))) float f32x4;

__device__ __forceinline__ unsigned short f2bf(float a) {
    unsigned int u = __float_as_uint(a);
    u = (u + 0x7fffu + ((u >> 16) & 1u)) >> 16;
    return (unsigned short)u;
}

// one v_cvt_pk_bf16_f32: D.lo = bf16(a), D.hi = bf16(b)
__device__ __forceinline__ unsigned int cvt_pk_bf16(float a, float b) {
    unsigned int r;
    asm("v_cvt_pk_bf16_f32 %0, %1, %2" : "=v"(r) : "v"(a), "v"(b));
    return r;
}

// branch-free tanh via v_exp_f32 + v_rcp_f32 (rel err ~1e-6)
__device__ __forceinline__ float fast_tanh(float v) {
    float a = __builtin_fabsf(v);
    float e = __builtin_amdgcn_exp2f(a * -2.88539008177793f);   // exp(-2a)
    float t = (1.0f - e) * __builtin_amdgcn_rcpf(1.0f + e);
    return __builtin_copysignf(t, v);
}

// ---------------------------------------------------------------------------
// Pack W1 (f32 [256][256], row k, col j) into bf16 MFMA b-frag layout:
// W1p[((kk*16 + cb)*64 + lane)*8 + e] = bf16(W1[(32*kk + 8*(lane>>4) + e)*256 + 16*cb + (lane&15)])
// ---------------------------------------------------------------------------
__global__ void pack_w1_k(const float* __restrict__ W1, unsigned short* __restrict__ W1p) {
    int p = blockIdx.x * 256 + threadIdx.x;   // 0 .. 65535
    int e  = p & 7;
    int l  = (p >> 3) & 63;
    int cb = (p >> 9) & 15;
    int kk = p >> 13;
    int k   = 32 * kk + 8 * (l >> 4) + e;
    int col = 16 * cb + (l & 15);
    W1p[p] = f2bf(W1[k * D + col]);
}

// ---------------------------------------------------------------------------
// Zero the accumulation workspace (accb[G*D] followed contiguously by den[G]).
// ---------------------------------------------------------------------------
__global__ void zero_k(float* __restrict__ p, int n) {
    int i = blockIdx.x * 256 + threadIdx.x;
    if (i < n) p[i] = 0.f;
}

// ---------------------------------------------------------------------------
// Fused: scores (bf16 MFMA) -> e=exp(score) -> unnormalized weighted scatter.
//   accb[g,:] += sum_i e_i * x_i   (f32 x held in registers, exact)
//   den[g]    += sum_i e_i
// No per-graph max needed: |score| <= ||W2||_1 + |b2| ~ 13, exp safe in f32,
// and attn = e/sum(e) is identical to the max-shifted form.
// Block: 256 threads = 4 waves, 64 rows per block; wave w owns cols [64w,64w+64).
// ---------------------------------------------------------------------------
__global__ void __launch_bounds__(256, 2)
fused_k(const float* __restrict__ x,
        const unsigned short* __restrict__ W1p,
        const float* __restrict__ b1,
        const float* __restrict__ W2,
        const float* __restrict__ b2,
        const int* __restrict__ batch, int N,
        float* __restrict__ accb, float* __restrict__ den) {
    __shared__ __align__(16) unsigned int Xl[64 * 128];  // 64 rows x 512B (bf16), XOR-swizzled
    __shared__ float scpart[4][64];
    __shared__ float red[4][256];
    __shared__ float erow[64];
    __shared__ int   bids[64];

    const int tid = threadIdx.x;
    const int w   = tid >> 6;       // wave id 0..3
    const int l   = tid & 63;       // lane in wave
    const int l15 = l & 15;
    const int g4  = l >> 4;         // 0..3
    const int row0 = blockIdx.x * 64;

    // ---- stage X tile into LDS as bf16 (swizzled) AND keep f32 copy in regs ----
    // thread (w,l): rows r = 4*it + w, float4 column chunk l (cols 4l..4l+3)
    float4 xv[16];
    const float4* x4 = reinterpret_cast<const float4*>(x);
    if (row0 + 64 <= N) {
        #pragma unroll
        for (int it = 0; it < 16; ++it) {
            int r = 4 * it + w;
            float4 v = x4[(size_t)(row0 + r) * 64 + l];
            xv[it] = v;
            unsigned int lo = cvt_pk_bf16(v.x, v.y);
            unsigned int hi = cvt_pk_bf16(v.z, v.w);
            int uidx = r * 128 + ((l * 2) ^ ((r & 7) << 2));
            *reinterpret_cast<uint2*>(&Xl[uidx]) = make_uint2(lo, hi);
        }
    } else {
        #pragma unroll
        for (int it = 0; it < 16; ++it) {
            int r = 4 * it + w;
            float4 v = make_float4(0.f, 0.f, 0.f, 0.f);
            if (row0 + r < N) v = x4[(size_t)(row0 + r) * 64 + l];
            xv[it] = v;
            unsigned int lo = cvt_pk_bf16(v.x, v.y);
            unsigned int hi = cvt_pk_bf16(v.z, v.w);
            int uidx = r * 128 + ((l * 2) ^ ((r & 7) << 2));
            *reinterpret_cast<uint2*>(&Xl[uidx]) = make_uint2(lo, hi);
        }
    }
    if (tid < 64) bids[tid] = batch[min(row0 + tid, N - 1)];
    __syncthreads();

    f32x4 acc[4][4];
    #pragma unroll
    for (int m = 0; m < 4; ++m)
        #pragma unroll
        for (int n = 0; n < 4; ++n)
            acc[m][n] = (f32x4){0.f, 0.f, 0.f, 0.f};

    #pragma unroll
    for (int kk = 0; kk < 8; ++kk) {
        bf16x8 bfr[4];
        #pragma unroll
        for (int n = 0; n < 4; ++n) {
            const bf16x8* bp = reinterpret_cast<const bf16x8*>(
                W1p + (size_t)(((kk * 16) + (w * 4 + n)) * 64 + l) * 8);
            bfr[n] = *bp;
        }
        bf16x8 afr[4];
        #pragma unroll
        for (int m = 0; m < 4; ++m) {
            int r = 16 * m + l15;
            int cbyte = 64 * kk + 16 * g4;
            int uidx = r * 128 + (((cbyte >> 2)) ^ ((r & 7) << 2));
            afr[m] = *reinterpret_cast<const bf16x8*>(&Xl[uidx]);
        }
        #pragma unroll
        for (int m = 0; m < 4; ++m)
            #pragma unroll
            for (int n = 0; n < 4; ++n)
                acc[m][n] = __builtin_amdgcn_mfma_f32_16x16x32_bf16(afr[m], bfr[n], acc[m][n], 0, 0, 0);
    }

    // ---- epilogue: +b1, fast_tanh, *W2, reduce over cols -> per-row score ----
    float part[4][4];
    #pragma unroll
    for (int m = 0; m < 4; ++m)
        #pragma unroll
        for (int r = 0; r < 4; ++r) part[m][r] = 0.f;

    #pragma unroll
    for (int n = 0; n < 4; ++n) {
        int col = 64 * w + 16 * n + l15;
        float b1v = b1[col];
        float w2v = W2[col];
        #pragma unroll
        for (int m = 0; m < 4; ++m)
            #pragma unroll
            for (int r = 0; r < 4; ++r) {
                float h = fast_tanh(acc[m][n][r] + b1v);
                part[m][r] += h * w2v;
            }
    }

    #pragma unroll
    for (int m = 0; m < 4; ++m)
        #pragma unroll
        for (int r = 0; r < 4; ++r) {
            float p = part[m][r];
            p += __shfl_xor(p, 8, 16);
            p += __shfl_xor(p, 4, 16);
            p += __shfl_xor(p, 2, 16);
            p += __shfl_xor(p, 1, 16);
            if (l15 == 0) scpart[w][16 * m + 4 * g4 + r] = p;
        }
    __syncthreads();

    if (tid < 64) {
        float s = scpart[0][tid] + scpart[1][tid] + scpart[2][tid] + scpart[3][tid] + b2[0];
        erow[tid] = (row0 + tid < N)
                  ? __builtin_amdgcn_exp2f(s * 1.4426950408889634f)
                  : 0.f;
    }
    __syncthreads();

    // ---- pooling: per graph in this block's row range, scatter-add ----
    const int g0 = bids[0], g1 = bids[63];
    for (int g = g0; g <= g1; ++g) {
        float4 a = make_float4(0.f, 0.f, 0.f, 0.f);
        #pragma unroll
        for (int it = 0; it < 16; ++it) {
            int r = 4 * it + w;
            float e = (bids[r] == g) ? erow[r] : 0.f;
            a.x += e * xv[it].x;
            a.y += e * xv[it].y;
            a.z += e * xv[it].z;
            a.w += e * xv[it].w;
        }
        red[w][l * 4 + 0] = a.x;
        red[w][l * 4 + 1] = a.y;
        red[w][l * 4 + 2] = a.z;
        red[w][l * 4 + 3] = a.w;
        __syncthreads();
        float s = red[0][tid] + red[1][tid] + red[2][tid] + red[3][tid];
        atomicAdd(&accb[(size_t)g * D + tid], s);
        if (w == 0) {
            float e = (bids[l] == g) ? erow[l] : 0.f;
            e += __shfl_xor(e, 32);
            e += __shfl_xor(e, 16);
            e += __shfl_xor(e, 8);
            e += __shfl_xor(e, 4);
            e += __shfl_xor(e, 2);
            e += __shfl_xor(e, 1);
            if (l == 0) atomicAdd(&den[g], e);
        }
        __syncthreads();   // red reused next g
    }
}

// ---------------------------------------------------------------------------
// out[g,:] = accb[g,:] / den[g]   (empty graph -> 0, matches reference)
// ---------------------------------------------------------------------------
__global__ void __launch_bounds__(256)
norm_k(const float* __restrict__ accb, const float* __restrict__ den,
       float* __restrict__ out) {
    int g = blockIdx.x;
    float dv = den[g];
    float inv = (dv > 0.f) ? 1.0f / dv : 0.f;
    out[(size_t)g * D + threadIdx.x] = accb[(size_t)g * D + threadIdx.x] * inv;
}

// ---------------------------------------------------------------------------
extern "C" void kernel_launch(void* const* d_in, const int* in_sizes, int n_in,
                              void* d_out, int out_size, void* d_ws, size_t ws_size,
                              hipStream_t stream) {
    const float* x     = (const float*)d_in[0];
    const int*   batch = (const int*)d_in[1];
    const float* W1    = (const float*)d_in[3];
    const float* b1    = (const float*)d_in[4];
    const float* W2    = (const float*)d_in[5];
    const float* b2    = (const float*)d_in[6];
    float* out = (float*)d_out;

    const int N = in_sizes[0] / D;
    const int G = out_size / D;

    char* ws = (char*)d_ws;
    unsigned short* W1p = (unsigned short*)ws;               // 128 KB
    float* accb = (float*)(ws + 131072);                     // G*D*4 bytes
    float* den  = (float*)(ws + 131072 + (size_t)G * D * 4); // G*4 bytes (contiguous after accb)

    zero_k<<<dim3((G * D + G + 255) / 256), dim3(256), 0, stream>>>(accb, G * D + G);
    pack_w1_k<<<dim3(256), dim3(256), 0, stream>>>(W1, W1p);
    fused_k<<<dim3((N + 63) / 64), dim3(256), 0, stream>>>(x, W1p, b1, W2, b2, batch, N, accb, den);
    norm_k<<<dim3(G), dim3(256), 0, stream>>>(accb, den, out);
}